// Round 7
// baseline (269.285 us; speedup 1.0000x reference)
//
#include <hip/hip_runtime.h>
#include <hip/hip_bf16.h>

#define MUL_Sc 256
#define DIM_Hc 640
#define IN_COLS 644
#define KF 768
#define NT 32

#define C0F 0.05103103630798287f
#define INV_SQRT3F 0.57735026918962576f

typedef __attribute__((ext_vector_type(8))) short short8;
typedef __attribute__((ext_vector_type(4))) float f32x4;

#define MFMA(a, b, c) __builtin_amdgcn_mfma_f32_16x16x32_bf16((a), (b), (c), 0, 0, 0)

__device__ __forceinline__ unsigned short f2bf(float x) {
    union { float f; unsigned u; } v; v.f = x;
    unsigned r = v.u + 0x7fffu + ((v.u >> 16) & 1u);   // RNE
    return (unsigned short)(r >> 16);
}

// async global -> LDS, 16B per lane; LDS dest is wave-uniform base + lane*16
__device__ __forceinline__ void gload_lds16(const unsigned short* g, unsigned short* l) {
    __builtin_amdgcn_global_load_lds((const __attribute__((address_space(1))) void*)g,
                                     (__attribute__((address_space(3))) void*)l, 16, 0, 0);
}

// ---- weight prep: fp32 [k][col] -> bf16 transposed [col][k] (unscaled, round-5 numerics) ----
// WT_sg 384x384: cols 0..255 scal (k<256: Wss, k>=256: Wvv), cols 256..383 gate (Wssg/Wvvg)
// WT_sv 128x256, WT_vs 128x128
__global__ void prep_weights(const float* __restrict__ Wss, const float* __restrict__ Wvv,
                             const float* __restrict__ Wssg, const float* __restrict__ Wvvg,
                             const float* __restrict__ Wsv, const float* __restrict__ Wvs,
                             unsigned short* __restrict__ wt) {
    int i = blockIdx.x * 256 + threadIdx.x;
    const int N_SG = 384 * 384;
    const int N_SV = 128 * 256;
    const int N_VS = 128 * 128;
    if (i < N_SG) {
        int col = i / 384, k = i % 384;
        float v;
        if (col < 256) v = (k < 256) ? Wss[k * 256 + col] : Wvv[(k - 256) * 256 + col];
        else { int c = col - 256; v = (k < 256) ? Wssg[k * 128 + c] : Wvvg[(k - 256) * 128 + c]; }
        wt[i] = f2bf(v);
    } else if (i < N_SG + N_SV) {
        int j = i - N_SG; int col = j >> 8, k = j & 255;
        wt[i] = f2bf(Wsv[k * 128 + col]);
    } else if (i < N_SG + N_SV + N_VS) {
        int j = i - N_SG - N_SV; int col = j >> 7, k = j & 127;
        wt[i] = f2bf(Wvs[k * 128 + col]);
    }
}

// ---- fused main kernel: weights streamed through LDS (async dbuf), feat in LDS ----
// feat row per node (bf16, 768): [ xs(0:256) | dot(256:384) | xv_k0(384:512) | xv_k1(512:640) | xv_k2(640:768) ]
// B panel LDS layout per BK=64 step: [col][8 chunks of 16B], chunk XOR-swizzled by (col&7)
__global__ __launch_bounds__(512, 2)
void fused_main(const float* __restrict__ din, const unsigned short* __restrict__ wt,
                const float* __restrict__ bias, float* __restrict__ out, int N) {
    __shared__ unsigned short feat[NT * KF];        // 48 KB
    __shared__ unsigned short ldsB[2][384 * 64];    // 2 x 48 KB
    __shared__ float psv[NT * 4];

    const int tid  = threadIdx.x;
    const int wave = tid >> 6;
    const int lane = tid & 63;
    const int n0   = blockIdx.x * NT;

    const unsigned short* WTsg = wt;
    const unsigned short* WTsv = wt + 384 * 384;
    const unsigned short* WTvs = wt + 384 * 384 + 128 * 256;

    // stage BK=64 k-slice `step` of WT[col][rs] into ldsB[buf]; nr rounds of 64 cols
    auto stage = [&](int buf, const unsigned short* W, int rs, int nr, int step) {
        unsigned short* lb = &ldsB[buf][0] + wave * 512;   // wave-uniform base (1KB/wave)
        #pragma unroll
        for (int m = 0; m < nr; ++m) {
            int slot = m * 512 + tid;
            int col  = slot >> 3;
            int k8   = (slot & 7) ^ (col & 7);             // inverse-swizzled SOURCE (rule 21)
            gload_lds16(W + col * rs + step * 64 + k8 * 8, lb + m * 4096);
        }
    };

    // issue first sg weight panel before feature staging (lands during it)
    stage(0, WTsg, 384, 6, 0);

    // ---------------- feature staging: 16 threads per node (round-5 verbatim) ----------------
    {
        const int g = tid >> 4;       // local node 0..31
        const int j = tid & 15;
        int n = n0 + g; if (n >= N) n = N - 1;
        const float* row = din + (size_t)n * IN_COLS;
        float ps  = row[DIM_Hc];
        float pv0 = row[DIM_Hc + 1], pv1 = row[DIM_Hc + 2], pv2 = row[DIM_Hc + 3];
        if (j == 0) { psv[g*4+0] = ps; psv[g*4+1] = pv0; psv[g*4+2] = pv1; psv[g*4+3] = pv2; }
        char* fb = (char*)feat;
        const int swz  = (g & 7) << 4;
        const int rowb = g * (KF * 2);

        {
            int c = 16 * j;
            float4 x0 = *(const float4*)(row + c);
            float4 x1 = *(const float4*)(row + c + 4);
            float4 x2 = *(const float4*)(row + c + 8);
            float4 x3 = *(const float4*)(row + c + 12);
            short8 p0, p1;
            p0[0]=(short)f2bf(x0.x); p0[1]=(short)f2bf(x0.y); p0[2]=(short)f2bf(x0.z); p0[3]=(short)f2bf(x0.w);
            p0[4]=(short)f2bf(x1.x); p0[5]=(short)f2bf(x1.y); p0[6]=(short)f2bf(x1.z); p0[7]=(short)f2bf(x1.w);
            p1[0]=(short)f2bf(x2.x); p1[1]=(short)f2bf(x2.y); p1[2]=(short)f2bf(x2.z); p1[3]=(short)f2bf(x2.w);
            p1[4]=(short)f2bf(x3.x); p1[5]=(short)f2bf(x3.y); p1[6]=(short)f2bf(x3.z); p1[7]=(short)f2bf(x3.w);
            *(short8*)(fb + ((rowb + c * 2) ^ swz))       = p0;
            *(short8*)(fb + ((rowb + (c + 8) * 2) ^ swz)) = p1;
        }
        {
            int u0 = 8 * j;
            const float* p = row + MUL_Sc + 3 * u0;
            float e[24];
            #pragma unroll
            for (int q = 0; q < 6; ++q) {
                float4 v = *(const float4*)(p + 4 * q);
                e[4*q+0] = v.x; e[4*q+1] = v.y; e[4*q+2] = v.z; e[4*q+3] = v.w;
            }
            short8 dp, k0, k1, k2;
            #pragma unroll
            for (int m = 0; m < 8; ++m) {
                float a = e[3*m], b = e[3*m+1], c = e[3*m+2];
                dp[m] = (short)f2bf((a * pv0 + b * pv1 + c * pv2) * INV_SQRT3F);
                k0[m] = (short)f2bf(a);
                k1[m] = (short)f2bf(b);
                k2[m] = (short)f2bf(c);
            }
            *(short8*)(fb + ((rowb + (256 + u0) * 2) ^ swz)) = dp;
            *(short8*)(fb + ((rowb + (384 + u0) * 2) ^ swz)) = k0;
            *(short8*)(fb + ((rowb + (512 + u0) * 2) ^ swz)) = k1;
            *(short8*)(fb + ((rowb + (640 + u0) * 2) ^ swz)) = k2;
        }
    }
    __syncthreads();   // drains feat ds_writes AND stage(0) gloads

    const int l15   = lane & 15;
    const int lkb   = (lane >> 4) << 3;
    const int chnk  = lane >> 4;            // 0..3
    const int rbase = (lane >> 4) << 2;
    const char* fbr = (const char*)feat;
    const int swzr  = (l15 & 7) << 4;

    float pss[2][4];
    #pragma unroll
    for (int s = 0; s < 2; ++s)
    #pragma unroll
    for (int i = 0; i < 4; ++i) pss[s][i] = psv[(s * 16 + rbase + i) * 4];

    f32x4 accS[3][2];
    #pragma unroll
    for (int t = 0; t < 3; ++t) { accS[t][0] = (f32x4){0,0,0,0}; accS[t][1] = (f32x4){0,0,0,0}; }
    f32x4 accA[2];
    accA[0] = (f32x4){0,0,0,0}; accA[1] = (f32x4){0,0,0,0};
    f32x4 accV[3][2];
    #pragma unroll
    for (int k = 0; k < 3; ++k) { accV[k][0] = (f32x4){0,0,0,0}; accV[k][1] = (f32x4){0,0,0,0}; }

    auto sgstep = [&](int buf, int step) {
        const char* B = (const char*)&ldsB[buf][0];
        #pragma unroll
        for (int ks = 0; ks < 2; ++ks) {
            int kf = step * 64 + ks * 32 + lkb;
            short8 a0 = *(const short8*)(fbr + ((l15 * 1536 + kf * 2) ^ swzr));
            short8 a1 = *(const short8*)(fbr + (((16 + l15) * 1536 + kf * 2) ^ swzr));
            int ch = ks * 4 + chnk;
            #pragma unroll
            for (int t = 0; t < 3; ++t) {
                int col = (wave + t * 8) * 16 + l15;
                short8 b = *(const short8*)(B + col * 128 + ((ch ^ (col & 7)) << 4));
                accS[t][0] = MFMA(a0, b, accS[t][0]);
                accS[t][1] = MFMA(a1, b, accS[t][1]);
            }
        }
    };
    auto svstep = [&](int buf, int step) {
        const char* B = (const char*)&ldsB[buf][0];
        #pragma unroll
        for (int ks = 0; ks < 2; ++ks) {
            int kf = step * 64 + ks * 32 + lkb;
            short8 a0 = *(const short8*)(fbr + ((l15 * 1536 + kf * 2) ^ swzr));
            short8 a1 = *(const short8*)(fbr + (((16 + l15) * 1536 + kf * 2) ^ swzr));
            int ch = ks * 4 + chnk;
            int col = wave * 16 + l15;
            short8 b = *(const short8*)(B + col * 128 + ((ch ^ (col & 7)) << 4));
            accA[0] = MFMA(a0, b, accA[0]);
            accA[1] = MFMA(a1, b, accA[1]);
        }
    };
    auto vsstep = [&](int buf, int step) {
        const char* B = (const char*)&ldsB[buf][0];
        #pragma unroll
        for (int ks = 0; ks < 2; ++ks) {
            int ch = ks * 4 + chnk;
            int col = wave * 16 + l15;
            short8 b = *(const short8*)(B + col * 128 + ((ch ^ (col & 7)) << 4));
            #pragma unroll
            for (int p = 0; p < 3; ++p) {
                int kf = 384 + p * 128 + step * 64 + ks * 32 + lkb;
                short8 a0 = *(const short8*)(fbr + ((l15 * 1536 + kf * 2) ^ swzr));
                short8 a1 = *(const short8*)(fbr + (((16 + l15) * 1536 + kf * 2) ^ swzr));
                accV[p][0] = MFMA(a0, b, accV[p][0]);
                accV[p][1] = MFMA(a1, b, accV[p][1]);
            }
        }
    };

    // ---- 2-phase pipeline: stage(next) -> compute(cur) -> barrier ----
    stage(1, WTsg, 384, 6, 1);  sgstep(0, 0);  __syncthreads();
    stage(0, WTsg, 384, 6, 2);  sgstep(1, 1);  __syncthreads();
    stage(1, WTsg, 384, 6, 3);  sgstep(0, 2);  __syncthreads();
    stage(0, WTsg, 384, 6, 4);  sgstep(1, 3);
    // K=0..255 (xs) done -> apply per-node ps before dot part
    #pragma unroll
    for (int t = 0; t < 3; ++t)
    #pragma unroll
    for (int s = 0; s < 2; ++s)
    #pragma unroll
    for (int i = 0; i < 4; ++i) accS[t][s][i] *= pss[s][i];
    __syncthreads();
    stage(1, WTsg, 384, 6, 5);  sgstep(0, 4);  __syncthreads();
    stage(0, WTsv, 256, 2, 0);  sgstep(1, 5);

    // scal epilogue: silu -> global ; gate -> sigmoid stays in registers
    #pragma unroll
    for (int t = 0; t < 2; ++t) {
        int col = (wave + t * 8) * 16 + l15;
        float bc = bias[col];
        #pragma unroll
        for (int s = 0; s < 2; ++s)
        #pragma unroll
        for (int i = 0; i < 4; ++i) {
            int n = n0 + s * 16 + rbase + i;
            if (n < N) {
                float sc = C0F * accS[t][s][i] + bc;
                out[(size_t)n * DIM_Hc + col] = sc / (1.f + __expf(-sc));
            }
        }
    }
    float sgr[2][4];
    #pragma unroll
    for (int s = 0; s < 2; ++s)
    #pragma unroll
    for (int i = 0; i < 4; ++i) sgr[s][i] = 1.f / (1.f + __expf(-C0F * accS[2][s][i]));
    __syncthreads();

    stage(1, WTsv, 256, 2, 1);  svstep(0, 0);  __syncthreads();
    stage(0, WTsv, 256, 2, 2);  svstep(1, 1);  __syncthreads();
    stage(1, WTsv, 256, 2, 3);  svstep(0, 2);  __syncthreads();
    stage(0, WTvs, 128, 2, 0);  svstep(1, 3);  __syncthreads();
    stage(1, WTvs, 128, 2, 1);  vsstep(0, 0);  __syncthreads();
                                vsstep(1, 1);

    // ---- vec epilogue: vec = C0*(a1*pv + v2*ps) * sigmoid(gate) ----
    {
        int u = wave * 16 + l15;
        #pragma unroll
        for (int s = 0; s < 2; ++s)
        #pragma unroll
        for (int i = 0; i < 4; ++i) {
            int nl = s * 16 + rbase + i;
            int n = n0 + nl;
            if (n >= N) continue;
            float sg  = sgr[s][i];
            float ps  = pss[s][i];
            float pv0 = psv[nl * 4 + 1], pv1 = psv[nl * 4 + 2], pv2 = psv[nl * 4 + 3];
            float av = accA[s][i];
            size_t ob = (size_t)n * DIM_Hc + MUL_Sc + 3 * u;
            out[ob + 0] = C0F * (av * pv0 + accV[0][s][i] * ps) * sg;
            out[ob + 1] = C0F * (av * pv1 + accV[1][s][i] * ps) * sg;
            out[ob + 2] = C0F * (av * pv2 + accV[2][s][i] * ps) * sg;
        }
    }
}

extern "C" void kernel_launch(void* const* d_in, const int* in_sizes, int n_in,
                              void* d_out, int out_size, void* d_ws, size_t ws_size,
                              hipStream_t stream) {
    const float* din  = (const float*)d_in[0];
    const float* Wss  = (const float*)d_in[1];
    const float* Wvv  = (const float*)d_in[2];
    const float* Wssg = (const float*)d_in[3];
    const float* Wvvg = (const float*)d_in[4];
    const float* Wsv  = (const float*)d_in[5];
    const float* Wvs  = (const float*)d_in[6];
    const float* bias = (const float*)d_in[7];
    float* out = (float*)d_out;
    unsigned short* wt = (unsigned short*)d_ws;

    const size_t WT_BYTES = (size_t)(384 * 384 + 128 * 256 + 128 * 128) * 2;
    if (ws_size < WT_BYTES) return;

    int N = in_sizes[0] / IN_COLS;

    int prep_total = 384 * 384 + 128 * 256 + 128 * 128;
    prep_weights<<<(prep_total + 255) / 256, 256, 0, stream>>>(Wss, Wvv, Wssg, Wvvg, Wsv, Wvs, wt);

    int nblocks = (N + NT - 1) / NT;
    fused_main<<<nblocks, 512, 0, stream>>>(din, wt, bias, out, N);
}